// Round 1
// baseline (275.401 us; speedup 1.0000x reference)
//
#include <hip/hip_runtime.h>
#include <hip/hip_cooperative_groups.h>
#include <math.h>

namespace cg = cooperative_groups;

// Spherical voxelization: points [B,N,3] f32 -> hist [B,1,5,30,15] f32
// B=16, N=65536, bins = 5*30*15 = 2250.
// R11: fuse the two dispatches into ONE cooperative kernel:
//   phase A: zero 16*BINS u32 accumulators in ws (agent-scope atomic stores,
//            overlapped with LDS hist build)   -> grid.sync()
//   phase B: per-block LDS u32 hist (same proven math as R10), then
//            agent-scope atomicAdd of nonzero bins into the accumulator
//            (2.3M adds into 144 KB, L2-resident) -> grid.sync()
//   phase C: first 36000 threads convert u32 -> f32 out.
// Removes the 2nd dispatch + its gap and 18.4 MB of intermediate ws traffic.
// Co-residency guarded by occupancy query; R10 2-kernel path kept as fallback.

constexpr int RAD_N = 5, AZI_N = 30, ELE_N = 15;
constexpr int BINS  = RAD_N * AZI_N * ELE_N;   // 2250
constexpr int BATCHES = 16;
constexpr int TOTAL_OUT = BATCHES * BINS;      // 36000
constexpr int BLOCK = 512;
constexpr int PPT   = 2;                       // points per thread
constexpr int PPB   = BLOCK * PPT;             // 1024
constexpr float FX_SCALE = 2097152.0f;         // 2^21
constexpr float FX_INV   = 1.0f / 2097152.0f;

__device__ __forceinline__ float fast_atan2_02pi(float y, float x) {
    const float PI_F     = 3.14159265358979f;
    const float TWO_PI_F = 6.28318530717959f;
    const float HALF_PI  = 1.57079632679490f;
    float ax = fabsf(x), ay = fabsf(y);
    float mx = fmaxf(ax, ay), mn = fminf(ax, ay);
    float t  = mn * __builtin_amdgcn_rcpf(mx);
    float t2 = t * t;
    float p = -0.01172120f;
    p = __builtin_fmaf(p, t2,  0.05265332f);
    p = __builtin_fmaf(p, t2, -0.11643287f);
    p = __builtin_fmaf(p, t2,  0.19354346f);
    p = __builtin_fmaf(p, t2, -0.33262347f);
    p = __builtin_fmaf(p, t2,  0.99997726f);
    float th = t * p;                          // [0, pi/4]
    th = (ay > ax) ? (HALF_PI - th) : th;      // [0, pi/2]
    th = (x < 0.0f) ? (PI_F - th) : th;        // [0, pi]
    th = (y < 0.0f) ? (TWO_PI_F - th) : th;    // [0, 2pi)
    return th;
}

__device__ __forceinline__ float fast_acos(float x) {
    const float PI_F = 3.14159265358979f;
    float a = fabsf(x);
    float p = -0.0012624911f;
    p = __builtin_fmaf(p, a,  0.0066700901f);
    p = __builtin_fmaf(p, a, -0.0170881256f);
    p = __builtin_fmaf(p, a,  0.0308918810f);
    p = __builtin_fmaf(p, a, -0.0501743046f);
    p = __builtin_fmaf(p, a,  0.0889789874f);
    p = __builtin_fmaf(p, a, -0.2145988016f);
    p = __builtin_fmaf(p, a,  1.5707963050f);
    float s = __builtin_amdgcn_sqrtf(1.0f - a);
    float r = s * p;
    return (x < 0.0f) ? (PI_F - r) : r;
}

__device__ __forceinline__ unsigned to_fx(float w) {
    float v = __builtin_fmaf(w, FX_SCALE, 0.5f);
    return (unsigned)fmaxf(v, 0.0f);
}

__device__ __forceinline__ void process_point(float x, float y, float z,
                                              unsigned* hist) {
    const float TWO_PI_F = (float)(6.283185307179586);
    const float PI_F     = (float)(3.141592653589793);
    const float tr       = (float)(2.0 / 5.0);
    const float sr       = (float)(2.0 / 5.0 / 2.0);
    const float tr_p_sr  = (float)(0.4 + 0.2);
    const float rhi_lo   = (float)(2.0 - 0.2);
    const float DES_R_F  = 2.0f;
    const float ta       = (float)(6.283185307179586 / 30.0);
    const float te       = (float)(3.141592653589793 / 15.0);
    const float se       = (float)(3.141592653589793 / 30.0);
    const float te_p_se  = (float)(3.141592653589793 / 15.0 + 3.141592653589793 / 30.0);
    const float te075    = (float)(0.75 * (3.141592653589793 / 15.0));
    const float pi_m_se  = (float)(3.141592653589793 - 3.141592653589793 / 30.0);
    const float inv_tr   = (float)(5.0 / 2.0);
    const float inv_ta   = (float)(30.0 / 6.283185307179586);
    const float inv_te   = (float)(15.0 / 3.141592653589793);

    float r = __builtin_amdgcn_sqrtf(x * x + y * y + z * z);
    if (r > DES_R_F) return;   // all 8 weights exactly 0 in reference

    float azi = fast_atan2_02pi(y, x);
    float cz = z * __builtin_amdgcn_rcpf(fmaxf(r, 1e-12f));
    cz = fminf(fmaxf(cz, -1.0f), 1.0f);
    float ele = fast_acos(cz);

    // ---- radial ----
    int ra = (int)(r * inv_tr);
    if (ra > RAD_N - 1) ra = RAD_N - 1;
    float cra = ((float)ra + 0.5f) * tr;
    int rb = (r > cra) ? ra + 1 : ra - 1;
    rb = (rb < 0) ? 1 : ((rb > RAD_N - 1) ? RAD_N - 2 : rb);
    float dra = fabsf(r - cra);
    float drb = fabsf(r - ((float)rb + 0.5f) * tr);
    {
        bool lowR  = r < sr;
        bool highR = (r > rhi_lo);
        if (lowR) {
            dra = (dra <= sr) ? 0.0f : ((dra > tr && dra <= tr_p_sr) ? tr : dra);
            drb = (drb <= sr) ? 0.0f : ((drb > tr && drb <= tr_p_sr) ? tr : drb);
        }
        if (highR) {
            if (dra > tr && dra <= tr_p_sr) dra = tr;
            if (drb > tr && drb <= tr_p_sr) drb = tr;
        }
    }
    float wra = 1.0f - dra * inv_tr;
    float wrb = 1.0f - drb * inv_tr;

    // ---- azimuth (circular) ----
    int aa = (int)(azi * inv_ta);
    if (aa > AZI_N - 1) aa = AZI_N - 1;
    float caa = ((float)aa + 0.5f) * ta;
    int ab = (azi > caa) ? aa + 1 : aa - 1;
    ab = (ab < 0) ? AZI_N - 1 : ((ab > AZI_N - 1) ? 0 : ab);
    float daa = fabsf(azi - caa);
    daa = fminf(daa, TWO_PI_F - daa);
    float dab = fabsf(azi - ((float)ab + 0.5f) * ta);
    dab = fminf(dab, TWO_PI_F - dab);
    float waa = 1.0f - daa * inv_ta;
    float wab = 1.0f - dab * inv_ta;

    // ---- elevation ----
    int ea = (int)(ele * inv_te);
    if (ea > ELE_N - 1) ea = ELE_N - 1;
    float cea = ((float)ea + 0.5f) * te;
    int eb = (ele > cea) ? ea + 1 : ea - 1;
    eb = (eb < 0) ? 1 : ((eb > ELE_N - 1) ? ELE_N - 2 : eb);
    float dea = fabsf(ele - cea);
    float deb = fabsf(ele - ((float)eb + 0.5f) * te);
    {
        bool lowE  = ele < se;
        bool highE = (ele > pi_m_se) && (ele <= PI_F);
        if (lowE) {
            dea = (dea <= se) ? 0.0f : ((dea > te && dea <= te_p_se) ? te : dea);
            deb = (deb <= se) ? 0.0f : ((deb > te && deb <= te_p_se) ? te : deb);
        }
        if (highE) {
            dea = (dea <= te075) ? 0.0f : ((dea > te && dea <= te_p_se) ? te : dea);
            deb = (deb <= te075) ? 0.0f : ((deb > te && deb <= te_p_se) ? te : deb);
        }
    }
    float wea = 1.0f - dea * inv_te;
    float web = 1.0f - deb * inv_te;

    int rbase_a = ra * (AZI_N * ELE_N), rbase_b = rb * (AZI_N * ELE_N);
    int abase_a = aa * ELE_N,           abase_b = ab * ELE_N;
    float w_aa = wra * waa, w_ab = wra * wab;
    float w_ba = wrb * waa, w_bb = wrb * wab;

    atomicAdd(&hist[rbase_a + abase_a + ea], to_fx(w_aa * wea));
    atomicAdd(&hist[rbase_a + abase_a + eb], to_fx(w_aa * web));
    atomicAdd(&hist[rbase_a + abase_b + ea], to_fx(w_ab * wea));
    atomicAdd(&hist[rbase_a + abase_b + eb], to_fx(w_ab * web));
    atomicAdd(&hist[rbase_b + abase_a + ea], to_fx(w_ba * wea));
    atomicAdd(&hist[rbase_b + abase_a + eb], to_fx(w_ba * web));
    atomicAdd(&hist[rbase_b + abase_b + ea], to_fx(w_bb * wea));
    atomicAdd(&hist[rbase_b + abase_b + eb], to_fx(w_bb * web));
}

// ---------------- R11: fused cooperative kernel ----------------
__global__ __launch_bounds__(BLOCK) void voxel_coop(
    const float* __restrict__ pts, unsigned* __restrict__ Z,
    float* __restrict__ out, int N, int blocksPerBatch)
{
    __shared__ unsigned hist[BINS];
    for (int j = threadIdx.x; j < BINS; j += BLOCK) hist[j] = 0u;

    // phase A: zero the global u32 accumulators (agent-scope, bypasses L1;
    // ws content is poison, so this must happen before any adds)
    const int gtid = blockIdx.x * BLOCK + (int)threadIdx.x;
    if (gtid < TOTAL_OUT)
        __hip_atomic_store(&Z[gtid], 0u, __ATOMIC_RELAXED, __HIP_MEMORY_SCOPE_AGENT);

    __syncthreads();

    // phase B: per-block LDS hist (identical math to R10)
    const int batch = blockIdx.x / blocksPerBatch;
    const int bib   = blockIdx.x % blocksPerBatch;
    const size_t batch_off = (size_t)batch * N;
    const int i0 = bib * PPB + (int)threadIdx.x * PPT;

    if (i0 + PPT <= N) {
        // 2 points = 6 floats at byte offset 24*tid (8-aligned): 3x float2
        const float2* src = (const float2*)(pts + (batch_off + i0) * 3);
        float2 q0 = src[0];
        float2 q1 = src[1];
        float2 q2 = src[2];
        process_point(q0.x, q0.y, q1.x, hist);
        process_point(q1.y, q2.x, q2.y, hist);
    } else {
        for (int k = 0; k < PPT; ++k) {
            int i = i0 + k;
            if (i < N) {
                size_t p = (batch_off + i) * 3;
                process_point(pts[p], pts[p + 1], pts[p + 2], hist);
            }
        }
    }

    __syncthreads();

    cg::this_grid().sync();   // all Z zeros landed

    // phase B2: merge nonzero LDS bins into the batch accumulator
    unsigned* zb = Z + (size_t)batch * BINS;
    for (int j = threadIdx.x; j < BINS; j += BLOCK) {
        unsigned v = hist[j];
        if (v)
            __hip_atomic_fetch_add(&zb[j], v, __ATOMIC_RELAXED,
                                   __HIP_MEMORY_SCOPE_AGENT);
    }

    cg::this_grid().sync();   // all adds landed

    // phase C: convert to f32 output
    if (gtid < TOTAL_OUT) {
        unsigned s = __hip_atomic_load(&Z[gtid], __ATOMIC_RELAXED,
                                       __HIP_MEMORY_SCOPE_AGENT);
        out[gtid] = (float)s * FX_INV;
    }
}

// ---------------- R10 fallback path (proven) ----------------
__global__ __launch_bounds__(BLOCK) void voxel_store(
    const float* __restrict__ pts, unsigned* __restrict__ ws_u,
    int N, int blocksPerBatch)
{
    __shared__ unsigned hist[BINS];
    for (int j = threadIdx.x; j < BINS; j += BLOCK) hist[j] = 0u;
    __syncthreads();

    const int batch = blockIdx.x / blocksPerBatch;
    const int bib   = blockIdx.x % blocksPerBatch;
    const size_t batch_off = (size_t)batch * N;
    const int i0 = bib * PPB + (int)threadIdx.x * PPT;

    if (i0 + PPT <= N) {
        const float2* src = (const float2*)(pts + (batch_off + i0) * 3);
        float2 q0 = src[0];
        float2 q1 = src[1];
        float2 q2 = src[2];
        process_point(q0.x, q0.y, q1.x, hist);
        process_point(q1.y, q2.x, q2.y, hist);
    } else {
        for (int k = 0; k < PPT; ++k) {
            int i = i0 + k;
            if (i < N) {
                size_t p = (batch_off + i) * 3;
                process_point(pts[p], pts[p + 1], pts[p + 2], hist);
            }
        }
    }

    __syncthreads();
    unsigned* wb = ws_u + (size_t)blockIdx.x * BINS;
    for (int j = threadIdx.x; j < BINS; j += BLOCK) wb[j] = hist[j];
}

__global__ __launch_bounds__(256) void reduce_convert(
    const unsigned* __restrict__ ws_u, float* __restrict__ out,
    int blocksPerBatch, int total)
{
    int idx = blockIdx.x * 256 + (int)threadIdx.x;
    if (idx >= total) return;
    int batch = idx / BINS;
    int bin   = idx - batch * BINS;
    const unsigned* src = ws_u + (size_t)batch * blocksPerBatch * BINS + bin;
    unsigned s0 = 0u, s1 = 0u, s2 = 0u, s3 = 0u;
    int k = 0;
    for (; k + 3 < blocksPerBatch; k += 4) {
        unsigned a0 = src[(size_t)(k + 0) * BINS];
        unsigned a1 = src[(size_t)(k + 1) * BINS];
        unsigned a2 = src[(size_t)(k + 2) * BINS];
        unsigned a3 = src[(size_t)(k + 3) * BINS];
        s0 += a0; s1 += a1; s2 += a2; s3 += a3;
    }
    for (; k < blocksPerBatch; ++k) s0 += src[(size_t)k * BINS];
    out[idx] = (float)((s0 + s1) + (s2 + s3)) * FX_INV;
}

extern "C" void kernel_launch(void* const* d_in, const int* in_sizes, int n_in,
                              void* d_out, int out_size, void* d_ws, size_t ws_size,
                              hipStream_t stream) {
    const float* pts = (const float*)d_in[0];
    float* out = (float*)d_out;

    const int B = BATCHES;
    int total = in_sizes[0] / 3;                 // B*N
    int N = total / B;                           // 65536
    int blocksPerBatch = (N + PPB - 1) / PPB;    // 64
    int grid = B * blocksPerBatch;               // 1024 = 4 blocks/CU x 256 CU

    unsigned* ws_u = (unsigned*)d_ws;

    // Guard cooperative co-residency once (host-side query; capture-safe).
    static int coop_ok = -1;
    if (coop_ok < 0) {
        int nb = 0;
        hipError_t e = hipOccupancyMaxActiveBlocksPerMultiprocessor(
            &nb, voxel_coop, BLOCK, 0);
        coop_ok = (e == hipSuccess && nb >= 4) ? 1 : 0;
    }

    if (coop_ok) {
        const float* a_pts = pts;
        unsigned*    a_z   = ws_u;
        float*       a_out = out;
        int          a_n   = N;
        int          a_bpb = blocksPerBatch;
        void* args[] = {(void*)&a_pts, (void*)&a_z, (void*)&a_out,
                        (void*)&a_n, (void*)&a_bpb};
        hipError_t e = hipLaunchCooperativeKernel(
            voxel_coop, dim3(grid), dim3(BLOCK), args, 0, stream);
        if (e == hipSuccess) return;
        coop_ok = 0;  // fall through to proven 2-kernel path
    }

    voxel_store<<<dim3(grid), dim3(BLOCK), 0, stream>>>(pts, ws_u, N, blocksPerBatch);
    int rtotal = B * BINS;                       // 36000
    reduce_convert<<<dim3((rtotal + 255) / 256), dim3(256), 0, stream>>>(
        ws_u, out, blocksPerBatch, rtotal);
}

// Round 2
// 69.237 us; speedup vs baseline: 3.9776x; 3.9776x over previous
//
#include <hip/hip_runtime.h>
#include <math.h>

// Spherical voxelization: points [B,N,3] f32 -> hist [B,1,5,30,15] f32
// B=16, N=65536, bins = 5*30*15 = 2250.
// R12: revert R11's cooperative fuse (grid.sync costs ~100us/sync on MI355X
// -- 8 non-coherent XCD L2s force system-scope flushes; measured 205us).
// Back to R10's proven 2-kernel structure (68.7us) plus two stage-1 cuts:
//  (1) packed ds_add_u64: the ELE bin pair (ea,eb) is always adjacent, so
//      the 8 scatter-adds collapse to 4 u64 adds. Odd-index 8B alignment is
//      handled by a shadow array offset one word (bufO), selected per lane.
//      Bit-exact vs R10 (lo->hi carry needs a per-block bin > 2^32, already
//      excluded by the u32-per-bin assumption R10 validated).
//  (2) wave-vote (__any) skip of the rare lowR/lowE/highE boundary fixups
//      (P(any lane) ~ 6-16%); highR is common (~36% of lanes) so it stays
//      unconditionally predicated.

constexpr int RAD_N = 5, AZI_N = 30, ELE_N = 15;
constexpr int BINS  = RAD_N * AZI_N * ELE_N;   // 2250
constexpr int BLOCK = 512;
constexpr int PPT   = 2;                       // points per thread
constexpr int PPB   = BLOCK * PPT;             // 1024
constexpr float FX_SCALE = 2097152.0f;         // 2^21
constexpr float FX_INV   = 1.0f / 2097152.0f;

__device__ __forceinline__ float fast_atan2_02pi(float y, float x) {
    const float PI_F     = 3.14159265358979f;
    const float TWO_PI_F = 6.28318530717959f;
    const float HALF_PI  = 1.57079632679490f;
    float ax = fabsf(x), ay = fabsf(y);
    float mx = fmaxf(ax, ay), mn = fminf(ax, ay);
    float t  = mn * __builtin_amdgcn_rcpf(mx);
    float t2 = t * t;
    float p = -0.01172120f;
    p = __builtin_fmaf(p, t2,  0.05265332f);
    p = __builtin_fmaf(p, t2, -0.11643287f);
    p = __builtin_fmaf(p, t2,  0.19354346f);
    p = __builtin_fmaf(p, t2, -0.33262347f);
    p = __builtin_fmaf(p, t2,  0.99997726f);
    float th = t * p;                          // [0, pi/4]
    th = (ay > ax) ? (HALF_PI - th) : th;      // [0, pi/2]
    th = (x < 0.0f) ? (PI_F - th) : th;        // [0, pi]
    th = (y < 0.0f) ? (TWO_PI_F - th) : th;    // [0, 2pi)
    return th;
}

__device__ __forceinline__ float fast_acos(float x) {
    const float PI_F = 3.14159265358979f;
    float a = fabsf(x);
    float p = -0.0012624911f;
    p = __builtin_fmaf(p, a,  0.0066700901f);
    p = __builtin_fmaf(p, a, -0.0170881256f);
    p = __builtin_fmaf(p, a,  0.0308918810f);
    p = __builtin_fmaf(p, a, -0.0501743046f);
    p = __builtin_fmaf(p, a,  0.0889789874f);
    p = __builtin_fmaf(p, a, -0.2145988016f);
    p = __builtin_fmaf(p, a,  1.5707963050f);
    float s = __builtin_amdgcn_sqrtf(1.0f - a);
    float r = s * p;
    return (x < 0.0f) ? (PI_F - r) : r;
}

__device__ __forceinline__ unsigned to_fx(float w) {
    float v = __builtin_fmaf(w, FX_SCALE, 0.5f);
    return (unsigned)fmaxf(v, 0.0f);
}

// One packed add covering bins (idx, idx+1): flo -> idx, fhi -> idx+1.
// Even idx lands 8-aligned in bufE; odd idx lands 8-aligned at bufO+1+idx
// (bufO is the shadow array pre-shifted one word).
__device__ __forceinline__ void emit_pair(unsigned* bufE, unsigned* bufO,
                                          int idx, float flo, float fhi) {
    unsigned long long v =
        ((unsigned long long)to_fx(fhi) << 32) | (unsigned long long)to_fx(flo);
    unsigned* base = (idx & 1) ? (bufO + 1) : bufE;
    atomicAdd((unsigned long long*)(base + idx), v);
}

__device__ __forceinline__ void process_point(float x, float y, float z,
                                              unsigned* bufE, unsigned* bufO) {
    const float TWO_PI_F = (float)(6.283185307179586);
    const float PI_F     = (float)(3.141592653589793);
    const float tr       = (float)(2.0 / 5.0);
    const float sr       = (float)(2.0 / 5.0 / 2.0);
    const float tr_p_sr  = (float)(0.4 + 0.2);
    const float rhi_lo   = (float)(2.0 - 0.2);
    const float DES_R_F  = 2.0f;
    const float ta       = (float)(6.283185307179586 / 30.0);
    const float te       = (float)(3.141592653589793 / 15.0);
    const float se       = (float)(3.141592653589793 / 30.0);
    const float te_p_se  = (float)(3.141592653589793 / 15.0 + 3.141592653589793 / 30.0);
    const float te075    = (float)(0.75 * (3.141592653589793 / 15.0));
    const float pi_m_se  = (float)(3.141592653589793 - 3.141592653589793 / 30.0);
    const float inv_tr   = (float)(5.0 / 2.0);
    const float inv_ta   = (float)(30.0 / 6.283185307179586);
    const float inv_te   = (float)(15.0 / 3.141592653589793);

    float r = __builtin_amdgcn_sqrtf(x * x + y * y + z * z);
    if (r > DES_R_F) return;   // all 8 weights exactly 0 in reference

    float azi = fast_atan2_02pi(y, x);
    float cz = z * __builtin_amdgcn_rcpf(fmaxf(r, 1e-12f));
    cz = fminf(fmaxf(cz, -1.0f), 1.0f);
    float ele = fast_acos(cz);

    // ---- radial ----
    int ra = (int)(r * inv_tr);
    if (ra > RAD_N - 1) ra = RAD_N - 1;
    float cra = ((float)ra + 0.5f) * tr;
    int rb = (r > cra) ? ra + 1 : ra - 1;
    rb = (rb < 0) ? 1 : ((rb > RAD_N - 1) ? RAD_N - 2 : rb);
    float dra = fabsf(r - cra);
    float drb = fabsf(r - ((float)rb + 0.5f) * tr);
    {
        bool lowR  = r < sr;
        bool highR = (r > rhi_lo);
        if (__any(lowR)) {             // P(any lane) ~6%: wave-skip
            if (lowR) {
                dra = (dra <= sr) ? 0.0f : ((dra > tr && dra <= tr_p_sr) ? tr : dra);
                drb = (drb <= sr) ? 0.0f : ((drb > tr && drb <= tr_p_sr) ? tr : drb);
            }
        }
        if (highR) {                   // common (~36% lanes): stay predicated
            if (dra > tr && dra <= tr_p_sr) dra = tr;
            if (drb > tr && drb <= tr_p_sr) drb = tr;
        }
    }
    float wra = 1.0f - dra * inv_tr;
    float wrb = 1.0f - drb * inv_tr;

    // ---- azimuth (circular) ----
    int aa = (int)(azi * inv_ta);
    if (aa > AZI_N - 1) aa = AZI_N - 1;
    float caa = ((float)aa + 0.5f) * ta;
    int ab = (azi > caa) ? aa + 1 : aa - 1;
    ab = (ab < 0) ? AZI_N - 1 : ((ab > AZI_N - 1) ? 0 : ab);
    float daa = fabsf(azi - caa);
    daa = fminf(daa, TWO_PI_F - daa);
    float dab = fabsf(azi - ((float)ab + 0.5f) * ta);
    dab = fminf(dab, TWO_PI_F - dab);
    float waa = 1.0f - daa * inv_ta;
    float wab = 1.0f - dab * inv_ta;

    // ---- elevation ----
    int ea = (int)(ele * inv_te);
    if (ea > ELE_N - 1) ea = ELE_N - 1;
    float cea = ((float)ea + 0.5f) * te;
    int eb = (ele > cea) ? ea + 1 : ea - 1;
    eb = (eb < 0) ? 1 : ((eb > ELE_N - 1) ? ELE_N - 2 : eb);
    float dea = fabsf(ele - cea);
    float deb = fabsf(ele - ((float)eb + 0.5f) * te);
    {
        bool lowE  = ele < se;
        bool highE = (ele > pi_m_se) && (ele <= PI_F);
        if (__any(lowE)) {             // P(any lane) ~16%: wave-skip
            if (lowE) {
                dea = (dea <= se) ? 0.0f : ((dea > te && dea <= te_p_se) ? te : dea);
                deb = (deb <= se) ? 0.0f : ((deb > te && deb <= te_p_se) ? te : deb);
            }
        }
        if (__any(highE)) {            // P(any lane) ~16%: wave-skip
            if (highE) {
                dea = (dea <= te075) ? 0.0f : ((dea > te && dea <= te_p_se) ? te : dea);
                deb = (deb <= te075) ? 0.0f : ((deb > te && deb <= te_p_se) ? te : deb);
            }
        }
    }
    float wea = 1.0f - dea * inv_te;
    float web = 1.0f - deb * inv_te;

    // ---- packed scatter: ELE pair (ea,eb) is always adjacent ----
    int elo   = (ea < eb) ? ea : eb;
    float wlo = (ea < eb) ? wea : web;
    float whi = (ea < eb) ? web : wea;

    int rbase_a = ra * (AZI_N * ELE_N), rbase_b = rb * (AZI_N * ELE_N);
    int abase_a = aa * ELE_N,           abase_b = ab * ELE_N;
    float w_aa = wra * waa, w_ab = wra * wab;
    float w_ba = wrb * waa, w_bb = wrb * wab;

    emit_pair(bufE, bufO, rbase_a + abase_a + elo, w_aa * wlo, w_aa * whi);
    emit_pair(bufE, bufO, rbase_a + abase_b + elo, w_ab * wlo, w_ab * whi);
    emit_pair(bufE, bufO, rbase_b + abase_a + elo, w_ba * wlo, w_ba * whi);
    emit_pair(bufE, bufO, rbase_b + abase_b + elo, w_bb * wlo, w_bb * whi);
}

// Stage 1: LDS u32 hist (split even/odd-aligned arrays) -> plain stores of
// partials to ws[block][bin]
__global__ __launch_bounds__(BLOCK) void voxel_store(
    const float* __restrict__ pts, unsigned* __restrict__ ws_u,
    int N, int blocksPerBatch)
{
    // bufE: pairs starting at even bin. bufO: pairs starting at odd bin,
    // pre-shifted one word so &bufO[1+idx] is 8-aligned for odd idx.
    // Max pair start = 2248 -> touches [2248],[2249] (E) / [2249],[2250] (O-raw).
    __shared__ __align__(8) unsigned bufE[BINS + 2];
    __shared__ __align__(8) unsigned bufO[BINS + 2];
    for (int j = threadIdx.x; j < BINS + 2; j += BLOCK) { bufE[j] = 0u; bufO[j] = 0u; }
    __syncthreads();

    const int batch = blockIdx.x / blocksPerBatch;
    const int bib   = blockIdx.x % blocksPerBatch;
    const size_t batch_off = (size_t)batch * N;
    const int i0 = bib * PPB + (int)threadIdx.x * PPT;

    if (i0 + PPT <= N) {
        // 2 points = 6 floats at byte offset 24*tid (8-aligned): 3x float2
        const float2* src = (const float2*)(pts + (batch_off + i0) * 3);
        float2 q0 = src[0];
        float2 q1 = src[1];
        float2 q2 = src[2];
        process_point(q0.x, q0.y, q1.x, bufE, bufO);
        process_point(q1.y, q2.x, q2.y, bufE, bufO);
    } else {
        for (int k = 0; k < PPT; ++k) {
            int i = i0 + k;
            if (i < N) {
                size_t p = (batch_off + i) * 3;
                process_point(pts[p], pts[p + 1], pts[p + 2], bufE, bufO);
            }
        }
    }

    __syncthreads();
    // bin j = bufE[j] (even-start lo + odd-j hi words) + bufO[j+1] (odd-start)
    unsigned* wb = ws_u + (size_t)blockIdx.x * BINS;
    for (int j = threadIdx.x; j < BINS; j += BLOCK) wb[j] = bufE[j] + bufO[j + 1];
}

// Stage 2: out[batch][bin] = (sum_k ws[batch*bpb+k][bin]) * 2^-21
__global__ __launch_bounds__(256) void reduce_convert(
    const unsigned* __restrict__ ws_u, float* __restrict__ out,
    int blocksPerBatch, int total)
{
    int idx = blockIdx.x * 256 + (int)threadIdx.x;
    if (idx >= total) return;
    int batch = idx / BINS;
    int bin   = idx - batch * BINS;
    const unsigned* src = ws_u + (size_t)batch * blocksPerBatch * BINS + bin;
    unsigned s0 = 0u, s1 = 0u, s2 = 0u, s3 = 0u;
    int k = 0;
    for (; k + 3 < blocksPerBatch; k += 4) {
        unsigned a0 = src[(size_t)(k + 0) * BINS];
        unsigned a1 = src[(size_t)(k + 1) * BINS];
        unsigned a2 = src[(size_t)(k + 2) * BINS];
        unsigned a3 = src[(size_t)(k + 3) * BINS];
        s0 += a0; s1 += a1; s2 += a2; s3 += a3;
    }
    for (; k < blocksPerBatch; ++k) s0 += src[(size_t)k * BINS];
    out[idx] = (float)((s0 + s1) + (s2 + s3)) * FX_INV;
}

extern "C" void kernel_launch(void* const* d_in, const int* in_sizes, int n_in,
                              void* d_out, int out_size, void* d_ws, size_t ws_size,
                              hipStream_t stream) {
    const float* pts = (const float*)d_in[0];
    float* out = (float*)d_out;

    const int B = 16;
    int total = in_sizes[0] / 3;                 // B*N
    int N = total / B;                           // 65536
    int blocksPerBatch = (N + PPB - 1) / PPB;    // 64
    int grid = B * blocksPerBatch;               // 1024 = 4 blocks/CU x 256 CU

    unsigned* ws_u = (unsigned*)d_ws;            // grid*BINS u32 = 9.2 MB
    voxel_store<<<dim3(grid), dim3(BLOCK), 0, stream>>>(pts, ws_u, N, blocksPerBatch);
    int rtotal = B * BINS;                       // 36000
    reduce_convert<<<dim3((rtotal + 255) / 256), dim3(256), 0, stream>>>(
        ws_u, out, blocksPerBatch, rtotal);
}

// Round 3
// 67.090 us; speedup vs baseline: 4.1049x; 1.0320x over previous
//
#include <hip/hip_runtime.h>
#include <math.h>

// Spherical voxelization: points [B,N,3] f32 -> hist [B,1,5,30,15] f32
// B=16, N=65536, bins = 5*30*15 = 2250.
// R13: decomposition model says total = 41.5us harness ws-poison fill
// (HBM-roofline, untouchable) + ~20us graph/reset overhead (untouchable)
// + ~7us controllable (stage1 + stage2 + gap). R12's null proved stage-1
// interior (LDS atomics, fixup VALU) is not the limiter, so attack the
// remaining linear-in-grid terms: PPT 2->4, grid 1024->512 (2 blocks/CU,
// 16 waves/CU). Halves ws traffic (9.2->4.6 MB), stage-2 depth (64->32),
// LDS init/writeout instances; input loads become aligned float4
// (48B/thread). Also the occupancy probe: if stage-1 is secretly big and
// latency-bound, this REGRESSES >= +3us -> revert grid and pivot.

constexpr int RAD_N = 5, AZI_N = 30, ELE_N = 15;
constexpr int BINS  = RAD_N * AZI_N * ELE_N;   // 2250
constexpr int BLOCK = 512;
constexpr int PPT   = 4;                       // points per thread
constexpr int PPB   = BLOCK * PPT;             // 2048
constexpr float FX_SCALE = 2097152.0f;         // 2^21
constexpr float FX_INV   = 1.0f / 2097152.0f;

__device__ __forceinline__ float fast_atan2_02pi(float y, float x) {
    const float PI_F     = 3.14159265358979f;
    const float TWO_PI_F = 6.28318530717959f;
    const float HALF_PI  = 1.57079632679490f;
    float ax = fabsf(x), ay = fabsf(y);
    float mx = fmaxf(ax, ay), mn = fminf(ax, ay);
    float t  = mn * __builtin_amdgcn_rcpf(mx);
    float t2 = t * t;
    float p = -0.01172120f;
    p = __builtin_fmaf(p, t2,  0.05265332f);
    p = __builtin_fmaf(p, t2, -0.11643287f);
    p = __builtin_fmaf(p, t2,  0.19354346f);
    p = __builtin_fmaf(p, t2, -0.33262347f);
    p = __builtin_fmaf(p, t2,  0.99997726f);
    float th = t * p;                          // [0, pi/4]
    th = (ay > ax) ? (HALF_PI - th) : th;      // [0, pi/2]
    th = (x < 0.0f) ? (PI_F - th) : th;        // [0, pi]
    th = (y < 0.0f) ? (TWO_PI_F - th) : th;    // [0, 2pi)
    return th;
}

__device__ __forceinline__ float fast_acos(float x) {
    const float PI_F = 3.14159265358979f;
    float a = fabsf(x);
    float p = -0.0012624911f;
    p = __builtin_fmaf(p, a,  0.0066700901f);
    p = __builtin_fmaf(p, a, -0.0170881256f);
    p = __builtin_fmaf(p, a,  0.0308918810f);
    p = __builtin_fmaf(p, a, -0.0501743046f);
    p = __builtin_fmaf(p, a,  0.0889789874f);
    p = __builtin_fmaf(p, a, -0.2145988016f);
    p = __builtin_fmaf(p, a,  1.5707963050f);
    float s = __builtin_amdgcn_sqrtf(1.0f - a);
    float r = s * p;
    return (x < 0.0f) ? (PI_F - r) : r;
}

__device__ __forceinline__ unsigned to_fx(float w) {
    float v = __builtin_fmaf(w, FX_SCALE, 0.5f);
    return (unsigned)fmaxf(v, 0.0f);
}

// One packed add covering bins (idx, idx+1): flo -> idx, fhi -> idx+1.
// Even idx lands 8-aligned in bufE; odd idx lands 8-aligned at bufO+1+idx
// (bufO is the shadow array pre-shifted one word).
__device__ __forceinline__ void emit_pair(unsigned* bufE, unsigned* bufO,
                                          int idx, float flo, float fhi) {
    unsigned long long v =
        ((unsigned long long)to_fx(fhi) << 32) | (unsigned long long)to_fx(flo);
    unsigned* base = (idx & 1) ? (bufO + 1) : bufE;
    atomicAdd((unsigned long long*)(base + idx), v);
}

__device__ __forceinline__ void process_point(float x, float y, float z,
                                              unsigned* bufE, unsigned* bufO) {
    const float TWO_PI_F = (float)(6.283185307179586);
    const float PI_F     = (float)(3.141592653589793);
    const float tr       = (float)(2.0 / 5.0);
    const float sr       = (float)(2.0 / 5.0 / 2.0);
    const float tr_p_sr  = (float)(0.4 + 0.2);
    const float rhi_lo   = (float)(2.0 - 0.2);
    const float DES_R_F  = 2.0f;
    const float ta       = (float)(6.283185307179586 / 30.0);
    const float te       = (float)(3.141592653589793 / 15.0);
    const float se       = (float)(3.141592653589793 / 30.0);
    const float te_p_se  = (float)(3.141592653589793 / 15.0 + 3.141592653589793 / 30.0);
    const float te075    = (float)(0.75 * (3.141592653589793 / 15.0));
    const float pi_m_se  = (float)(3.141592653589793 - 3.141592653589793 / 30.0);
    const float inv_tr   = (float)(5.0 / 2.0);
    const float inv_ta   = (float)(30.0 / 6.283185307179586);
    const float inv_te   = (float)(15.0 / 3.141592653589793);

    float r = __builtin_amdgcn_sqrtf(x * x + y * y + z * z);
    if (r > DES_R_F) return;   // all 8 weights exactly 0 in reference

    float azi = fast_atan2_02pi(y, x);
    float cz = z * __builtin_amdgcn_rcpf(fmaxf(r, 1e-12f));
    cz = fminf(fmaxf(cz, -1.0f), 1.0f);
    float ele = fast_acos(cz);

    // ---- radial ----
    int ra = (int)(r * inv_tr);
    if (ra > RAD_N - 1) ra = RAD_N - 1;
    float cra = ((float)ra + 0.5f) * tr;
    int rb = (r > cra) ? ra + 1 : ra - 1;
    rb = (rb < 0) ? 1 : ((rb > RAD_N - 1) ? RAD_N - 2 : rb);
    float dra = fabsf(r - cra);
    float drb = fabsf(r - ((float)rb + 0.5f) * tr);
    {
        bool lowR  = r < sr;
        bool highR = (r > rhi_lo);
        if (__any(lowR)) {             // P(any lane) ~6%: wave-skip
            if (lowR) {
                dra = (dra <= sr) ? 0.0f : ((dra > tr && dra <= tr_p_sr) ? tr : dra);
                drb = (drb <= sr) ? 0.0f : ((drb > tr && drb <= tr_p_sr) ? tr : drb);
            }
        }
        if (highR) {                   // common (~36% lanes): stay predicated
            if (dra > tr && dra <= tr_p_sr) dra = tr;
            if (drb > tr && drb <= tr_p_sr) drb = tr;
        }
    }
    float wra = 1.0f - dra * inv_tr;
    float wrb = 1.0f - drb * inv_tr;

    // ---- azimuth (circular) ----
    int aa = (int)(azi * inv_ta);
    if (aa > AZI_N - 1) aa = AZI_N - 1;
    float caa = ((float)aa + 0.5f) * ta;
    int ab = (azi > caa) ? aa + 1 : aa - 1;
    ab = (ab < 0) ? AZI_N - 1 : ((ab > AZI_N - 1) ? 0 : ab);
    float daa = fabsf(azi - caa);
    daa = fminf(daa, TWO_PI_F - daa);
    float dab = fabsf(azi - ((float)ab + 0.5f) * ta);
    dab = fminf(dab, TWO_PI_F - dab);
    float waa = 1.0f - daa * inv_ta;
    float wab = 1.0f - dab * inv_ta;

    // ---- elevation ----
    int ea = (int)(ele * inv_te);
    if (ea > ELE_N - 1) ea = ELE_N - 1;
    float cea = ((float)ea + 0.5f) * te;
    int eb = (ele > cea) ? ea + 1 : ea - 1;
    eb = (eb < 0) ? 1 : ((eb > ELE_N - 1) ? ELE_N - 2 : eb);
    float dea = fabsf(ele - cea);
    float deb = fabsf(ele - ((float)eb + 0.5f) * te);
    {
        bool lowE  = ele < se;
        bool highE = (ele > pi_m_se) && (ele <= PI_F);
        if (__any(lowE)) {             // P(any lane) ~16%: wave-skip
            if (lowE) {
                dea = (dea <= se) ? 0.0f : ((dea > te && dea <= te_p_se) ? te : dea);
                deb = (deb <= se) ? 0.0f : ((deb > te && deb <= te_p_se) ? te : deb);
            }
        }
        if (__any(highE)) {            // P(any lane) ~16%: wave-skip
            if (highE) {
                dea = (dea <= te075) ? 0.0f : ((dea > te && dea <= te_p_se) ? te : dea);
                deb = (deb <= te075) ? 0.0f : ((deb > te && deb <= te_p_se) ? te : deb);
            }
        }
    }
    float wea = 1.0f - dea * inv_te;
    float web = 1.0f - deb * inv_te;

    // ---- packed scatter: ELE pair (ea,eb) is always adjacent ----
    int elo   = (ea < eb) ? ea : eb;
    float wlo = (ea < eb) ? wea : web;
    float whi = (ea < eb) ? web : wea;

    int rbase_a = ra * (AZI_N * ELE_N), rbase_b = rb * (AZI_N * ELE_N);
    int abase_a = aa * ELE_N,           abase_b = ab * ELE_N;
    float w_aa = wra * waa, w_ab = wra * wab;
    float w_ba = wrb * waa, w_bb = wrb * wab;

    emit_pair(bufE, bufO, rbase_a + abase_a + elo, w_aa * wlo, w_aa * whi);
    emit_pair(bufE, bufO, rbase_a + abase_b + elo, w_ab * wlo, w_ab * whi);
    emit_pair(bufE, bufO, rbase_b + abase_a + elo, w_ba * wlo, w_ba * whi);
    emit_pair(bufE, bufO, rbase_b + abase_b + elo, w_bb * wlo, w_bb * whi);
}

// Stage 1: LDS u32 hist (split even/odd-aligned arrays) -> plain stores of
// partials to ws[block][bin]
__global__ __launch_bounds__(BLOCK) void voxel_store(
    const float* __restrict__ pts, unsigned* __restrict__ ws_u,
    int N, int blocksPerBatch)
{
    // bufE: pairs starting at even bin. bufO: pairs starting at odd bin,
    // pre-shifted one word so &bufO[1+idx] is 8-aligned for odd idx.
    __shared__ __align__(8) unsigned bufE[BINS + 2];
    __shared__ __align__(8) unsigned bufO[BINS + 2];
    for (int j = threadIdx.x; j < BINS + 2; j += BLOCK) { bufE[j] = 0u; bufO[j] = 0u; }
    __syncthreads();

    const int batch = blockIdx.x / blocksPerBatch;
    const int bib   = blockIdx.x % blocksPerBatch;
    const size_t batch_off = (size_t)batch * N;
    const int i0 = bib * PPB + (int)threadIdx.x * PPT;

    if (i0 + PPT <= N) {
        // 4 points = 12 floats at byte offset 48*tid (16-aligned): 3x float4
        const float4* src = (const float4*)(pts + (batch_off + i0) * 3);
        float4 v0 = src[0];
        float4 v1 = src[1];
        float4 v2 = src[2];
        process_point(v0.x, v0.y, v0.z, bufE, bufO);
        process_point(v0.w, v1.x, v1.y, bufE, bufO);
        process_point(v1.z, v1.w, v2.x, bufE, bufO);
        process_point(v2.y, v2.z, v2.w, bufE, bufO);
    } else {
        for (int k = 0; k < PPT; ++k) {
            int i = i0 + k;
            if (i < N) {
                size_t p = (batch_off + i) * 3;
                process_point(pts[p], pts[p + 1], pts[p + 2], bufE, bufO);
            }
        }
    }

    __syncthreads();
    // bin j = bufE[j] (even-start lo + odd-j hi words) + bufO[j+1] (odd-start)
    unsigned* wb = ws_u + (size_t)blockIdx.x * BINS;
    for (int j = threadIdx.x; j < BINS; j += BLOCK) wb[j] = bufE[j] + bufO[j + 1];
}

// Stage 2: out[batch][bin] = (sum_k ws[batch*bpb+k][bin]) * 2^-21
__global__ __launch_bounds__(256) void reduce_convert(
    const unsigned* __restrict__ ws_u, float* __restrict__ out,
    int blocksPerBatch, int total)
{
    int idx = blockIdx.x * 256 + (int)threadIdx.x;
    if (idx >= total) return;
    int batch = idx / BINS;
    int bin   = idx - batch * BINS;
    const unsigned* src = ws_u + (size_t)batch * blocksPerBatch * BINS + bin;
    unsigned s0 = 0u, s1 = 0u, s2 = 0u, s3 = 0u;
    int k = 0;
    for (; k + 3 < blocksPerBatch; k += 4) {
        unsigned a0 = src[(size_t)(k + 0) * BINS];
        unsigned a1 = src[(size_t)(k + 1) * BINS];
        unsigned a2 = src[(size_t)(k + 2) * BINS];
        unsigned a3 = src[(size_t)(k + 3) * BINS];
        s0 += a0; s1 += a1; s2 += a2; s3 += a3;
    }
    for (; k < blocksPerBatch; ++k) s0 += src[(size_t)k * BINS];
    out[idx] = (float)((s0 + s1) + (s2 + s3)) * FX_INV;
}

extern "C" void kernel_launch(void* const* d_in, const int* in_sizes, int n_in,
                              void* d_out, int out_size, void* d_ws, size_t ws_size,
                              hipStream_t stream) {
    const float* pts = (const float*)d_in[0];
    float* out = (float*)d_out;

    const int B = 16;
    int total = in_sizes[0] / 3;                 // B*N
    int N = total / B;                           // 65536
    int blocksPerBatch = (N + PPB - 1) / PPB;    // 32
    int grid = B * blocksPerBatch;               // 512 = 2 blocks/CU x 256 CU

    unsigned* ws_u = (unsigned*)d_ws;            // grid*BINS u32 = 4.6 MB
    voxel_store<<<dim3(grid), dim3(BLOCK), 0, stream>>>(pts, ws_u, N, blocksPerBatch);
    int rtotal = B * BINS;                       // 36000
    reduce_convert<<<dim3((rtotal + 255) / 256), dim3(256), 0, stream>>>(
        ws_u, out, blocksPerBatch, rtotal);
}